// Round 1
// baseline (3294.671 us; speedup 1.0000x reference)
//
#include <hip/hip_runtime.h>
#include <math.h>

// ---------------- problem constants ----------------
namespace {
constexpr int BN = 64;        // batch
constexpr int CH = 8;         // state channels
constexpr int NF = 64;        // hidden channels
constexpr int HW = 1024;      // 32*32
constexpr int NS = BN*CH*HW;  // 524288 state elems
constexpr int NH = BN*NF*HW;  // 4194304 hidden elems

// dopri5 tableau (float32, rounded from double like the reference)
constexpr float C2f = 0.2f, C3f = 0.3f, C4f = 0.8f, C5f = (float)(8.0/9.0);
constexpr float A21 = 0.2f;
constexpr float A31 = (float)(3.0/40.0),  A32 = (float)(9.0/40.0);
constexpr float A41 = (float)(44.0/45.0), A42 = (float)(-56.0/15.0), A43 = (float)(32.0/9.0);
constexpr float A51 = (float)(19372.0/6561.0), A52 = (float)(-25360.0/2187.0),
                A53 = (float)(64448.0/6561.0), A54 = (float)(-212.0/729.0);
constexpr float A61 = (float)(9017.0/3168.0), A62 = (float)(-355.0/33.0),
                A63 = (float)(46732.0/5247.0), A64 = (float)(49.0/176.0),
                A65 = (float)(-5103.0/18656.0);
constexpr float B1c = (float)(35.0/384.0), B3c = (float)(500.0/1113.0),
                B4c = (float)(125.0/192.0), B5c = (float)(-2187.0/6784.0),
                B6c = (float)(11.0/84.0);
constexpr float E1c = (float)(71.0/57600.0), E3c = (float)(-71.0/16695.0),
                E4c = (float)(71.0/1920.0), E5c = (float)(-17253.0/339200.0),
                E6c = (float)(22.0/525.0),  E7c = (float)(-1.0/40.0);
constexpr float RTOL = 1e-3f, ATOL = 1e-3f;

// ws layout in floats.  scalars: [0]=t [1]=dt [2]=adv [3]=done
constexpr size_t OFF_SC   = 0;
constexpr size_t OFF_PART = 16;                 // 256 partial sums
constexpr size_t OFF_Y    = 1024;
constexpr size_t OFF_Y5   = OFF_Y  + (size_t)NS;
constexpr size_t OFF_K    = OFF_Y5 + (size_t)NS;   // 7 * NS  (k1..k7)
constexpr size_t OFF_H1   = OFF_K  + 7*(size_t)NS;
constexpr size_t OFF_H2   = OFF_H1 + (size_t)NH;
// total = 1024 + 9*NS + 2*NH floats = 52.4 MB
}

struct Coefs { float a[5]; };

// ---------------- init: y0 = concat(x, zeros), scalars ----------------
__global__ __launch_bounds__(256)
void k_init(const float* __restrict__ x, float* __restrict__ y, float* __restrict__ sc)
{
    int idx = blockIdx.x*256 + threadIdx.x;   // < NS
    int b = idx >> 13;           // / (8*1024)
    int c = (idx >> 10) & 7;
    int p = idx & 1023;
    y[idx] = (c < 3) ? x[(size_t)(b*3 + c)*1024 + p] : 0.0f;
    if (idx == 0) { sc[0] = 0.0f; sc[1] = 0.1f; sc[2] = 0.0f; sc[3] = 0.0f; }
}

// ---------------- conv1: z = src + dtc*sum(a_j k_j); 1x1 conv 9->64 + relu ----------------
__global__ __launch_bounds__(256)
void k_conv1(const float* __restrict__ sc, const float* __restrict__ src,
             const float* __restrict__ kb, int ncoef, Coefs cf, float ct,
             const float* __restrict__ w1, const float* __restrict__ b1,
             float* __restrict__ h1)
{
    if (sc[3] != 0.0f) return;
    __shared__ __align__(16) float s_wt[8][64];
    __shared__ float s_w0[64];
    __shared__ float s_b[64];
    int tid = threadIdx.x;
    if (tid < 64) {
        s_b[tid]  = b1[tid];
        s_w0[tid] = w1[tid*9];
        #pragma unroll
        for (int c = 0; c < 8; c++) s_wt[c][tid] = w1[tid*9 + 1 + c];
    }
    __syncthreads();
    float t = sc[0], dt = sc[1];
    float dtc = fminf(dt, 1.0f - t);
    float ts  = t + ct*dtc;
    int gid = blockIdx.x*256 + tid;
    int b = gid >> 10, p = gid & 1023;

    float z[8];
    #pragma unroll
    for (int c = 0; c < 8; c++) {
        size_t idx = (size_t)(b*8 + c)*HW + p;
        float s = 0.0f;
        for (int j = 0; j < ncoef; j++) s += cf.a[j]*kb[(size_t)j*NS + idx];
        z[c] = src[idx] + dtc*s;
    }
    float acc[64];
    #pragma unroll
    for (int o = 0; o < 64; o++) acc[o] = fmaf(ts, s_w0[o], s_b[o]);
    #pragma unroll
    for (int c = 0; c < 8; c++) {
        float zc = z[c];
        const float4* w4 = reinterpret_cast<const float4*>(&s_wt[c][0]);
        #pragma unroll
        for (int q = 0; q < 16; q++) {
            float4 w = w4[q];
            acc[4*q+0] = fmaf(w.x, zc, acc[4*q+0]);
            acc[4*q+1] = fmaf(w.y, zc, acc[4*q+1]);
            acc[4*q+2] = fmaf(w.z, zc, acc[4*q+2]);
            acc[4*q+3] = fmaf(w.w, zc, acc[4*q+3]);
        }
    }
    size_t ob = (size_t)b*NF*HW + p;
    #pragma unroll
    for (int o = 0; o < 64; o++) h1[ob + (size_t)o*HW] = fmaxf(acc[o], 0.0f);
}

// ---------------- conv2: 3x3, 65->64 (ch0 = t), pad 1, relu ----------------
__global__ __launch_bounds__(256)
void k_conv2(const float* __restrict__ sc, const float* __restrict__ h1,
             const float* __restrict__ w2, const float* __restrict__ b2,
             float* __restrict__ h2, float ct)
{
    if (sc[3] != 0.0f) return;
    __shared__ __align__(16) float s_in[16*18*34];
    __shared__ __align__(16) float s_w[2304];       // (ic*9+tap)*16 + oc
    int tid = threadIdx.x;
    int b  = blockIdx.x;
    int rt = blockIdx.y;       // row tile: rows rt*16 .. rt*16+15
    int og = blockIdx.z;       // oc group of 16
    int ocb = og*16;
    int col = tid & 31;
    int r0  = tid >> 5;        // 0..7
    int g0  = rt*16 + r0;
    int g1  = g0 + 8;

    float t = sc[0], dt = sc[1];
    float dtc = fminf(dt, 1.0f - t);
    float ts  = t + ct*dtc;

    float acc0[16], acc1[16];
    #pragma unroll
    for (int o = 0; o < 16; o++) {
        float s0 = 0.0f, s1 = 0.0f;
        #pragma unroll
        for (int kh = 0; kh < 3; kh++) {
            bool v0 = (unsigned)(g0 + kh - 1) < 32u;
            bool v1 = (unsigned)(g1 + kh - 1) < 32u;
            #pragma unroll
            for (int kw = 0; kw < 3; kw++) {
                bool vc = (unsigned)(col + kw - 1) < 32u;
                float wv = w2[(ocb + o)*585 + kh*3 + kw];   // t-channel weights
                if (vc && v0) s0 += wv;
                if (vc && v1) s1 += wv;
            }
        }
        float bb = b2[ocb + o];
        acc0[o] = fmaf(ts, s0, bb);
        acc1[o] = fmaf(ts, s1, bb);
    }

    for (int cc = 0; cc < 4; cc++) {
        int ic0 = cc*16;
        for (int idx = tid; idx < 16*18*34; idx += 256) {
            int ic  = idx / 612;
            int rem = idx - ic*612;
            int lr  = rem / 34;
            int lc  = rem - lr*34;
            int gr  = rt*16 - 1 + lr;
            int gc  = lc - 1;
            float v = 0.0f;
            if ((unsigned)gr < 32u && (unsigned)gc < 32u)
                v = h1[(size_t)((b*64 + ic0 + ic)*32 + gr)*32 + gc];
            s_in[idx] = v;
        }
        for (int idx = tid; idx < 2304; idx += 256) {
            int oc  = idx / 144;
            int rem = idx - oc*144;        // ic*9 + tap
            s_w[rem*16 + oc] = w2[(ocb + oc)*585 + (1 + ic0)*9 + rem];
        }
        __syncthreads();

        #pragma unroll 4
        for (int ic = 0; ic < 16; ic++) {
            #pragma unroll
            for (int kh = 0; kh < 3; kh++) {
                const float* rowa = &s_in[(ic*18 + r0 + kh)*34 + col];
                const float* rowb = &s_in[(ic*18 + r0 + 8 + kh)*34 + col];
                float a0 = rowa[0], a1 = rowa[1], a2 = rowa[2];
                float e0 = rowb[0], e1 = rowb[1], e2 = rowb[2];
                #pragma unroll
                for (int kw = 0; kw < 3; kw++) {
                    const float4* wp = reinterpret_cast<const float4*>(&s_w[((ic*3 + kh)*3 + kw)*16]);
                    float iv0 = (kw == 0) ? a0 : ((kw == 1) ? a1 : a2);
                    float iv1 = (kw == 0) ? e0 : ((kw == 1) ? e1 : e2);
                    #pragma unroll
                    for (int q = 0; q < 4; q++) {
                        float4 w = wp[q];
                        acc0[4*q+0] = fmaf(w.x, iv0, acc0[4*q+0]);
                        acc0[4*q+1] = fmaf(w.y, iv0, acc0[4*q+1]);
                        acc0[4*q+2] = fmaf(w.z, iv0, acc0[4*q+2]);
                        acc0[4*q+3] = fmaf(w.w, iv0, acc0[4*q+3]);
                        acc1[4*q+0] = fmaf(w.x, iv1, acc1[4*q+0]);
                        acc1[4*q+1] = fmaf(w.y, iv1, acc1[4*q+1]);
                        acc1[4*q+2] = fmaf(w.z, iv1, acc1[4*q+2]);
                        acc1[4*q+3] = fmaf(w.w, iv1, acc1[4*q+3]);
                    }
                }
            }
        }
        __syncthreads();
    }
    #pragma unroll
    for (int o = 0; o < 16; o++) {
        h2[(size_t)((b*64 + ocb + o)*32 + g0)*32 + col] = fmaxf(acc0[o], 0.0f);
        h2[(size_t)((b*64 + ocb + o)*32 + g1)*32 + col] = fmaxf(acc1[o], 0.0f);
    }
}

// ---------------- conv3: 1x1, 65->8 (ch0 = t), no relu ----------------
__global__ __launch_bounds__(256)
void k_conv3(const float* __restrict__ sc, const float* __restrict__ h2,
             const float* __restrict__ w3, const float* __restrict__ b3,
             float* __restrict__ kout, float ct)
{
    if (sc[3] != 0.0f) return;
    __shared__ __align__(16) float s_wt[64][8];
    __shared__ float s_w0[8];
    __shared__ float s_b[8];
    int tid = threadIdx.x;
    if (tid < 64) {
        #pragma unroll
        for (int o = 0; o < 8; o++) s_wt[tid][o] = w3[o*65 + 1 + tid];
        if (tid < 8) { s_w0[tid] = w3[tid*65]; s_b[tid] = b3[tid]; }
    }
    __syncthreads();
    float t = sc[0], dt = sc[1];
    float dtc = fminf(dt, 1.0f - t);
    float ts  = t + ct*dtc;
    int gid = blockIdx.x*256 + tid;
    int b = gid >> 10, p = gid & 1023;

    float acc[8];
    #pragma unroll
    for (int o = 0; o < 8; o++) acc[o] = fmaf(ts, s_w0[o], s_b[o]);
    #pragma unroll 8
    for (int c = 0; c < 64; c++) {
        float hv = h2[(size_t)(b*64 + c)*HW + p];
        const float4* w4 = reinterpret_cast<const float4*>(&s_wt[c][0]);
        float4 wA = w4[0], wB = w4[1];
        acc[0] = fmaf(wA.x, hv, acc[0]);
        acc[1] = fmaf(wA.y, hv, acc[1]);
        acc[2] = fmaf(wA.z, hv, acc[2]);
        acc[3] = fmaf(wA.w, hv, acc[3]);
        acc[4] = fmaf(wB.x, hv, acc[4]);
        acc[5] = fmaf(wB.y, hv, acc[5]);
        acc[6] = fmaf(wB.z, hv, acc[6]);
        acc[7] = fmaf(wB.w, hv, acc[7]);
    }
    #pragma unroll
    for (int o = 0; o < 8; o++) kout[(size_t)(b*8 + o)*HW + p] = acc[o];
}

// ---------------- y5 = y + dt*(B.k) ----------------
__global__ __launch_bounds__(256)
void k_y5(const float* __restrict__ sc, const float4* __restrict__ y,
          const float4* __restrict__ kb, float4* __restrict__ y5)
{
    if (sc[3] != 0.0f) return;
    float t = sc[0], dt = sc[1];
    float dtc = fminf(dt, 1.0f - t);
    const int n4 = NS/4;
    int i = blockIdx.x*256 + threadIdx.x;
    float4 yv = y[i];
    float4 k1 = kb[i], k3 = kb[2*n4 + i], k4 = kb[3*n4 + i], k5 = kb[4*n4 + i], k6 = kb[5*n4 + i];
    float4 r;
    r.x = yv.x + dtc*(B1c*k1.x + B3c*k3.x + B4c*k4.x + B5c*k5.x + B6c*k6.x);
    r.y = yv.y + dtc*(B1c*k1.y + B3c*k3.y + B4c*k4.y + B5c*k5.y + B6c*k6.y);
    r.z = yv.z + dtc*(B1c*k1.z + B3c*k3.z + B4c*k4.z + B5c*k5.z + B6c*k6.z);
    r.w = yv.w + dtc*(B1c*k1.w + B3c*k3.w + B4c*k4.w + B5c*k5.w + B6c*k6.w);
    y5[i] = r;
}

// ---------------- err reduce ----------------
__device__ __forceinline__ float err_comp(float dtc, float yv, float y5v,
    float k1, float k3, float k4, float k5, float k6, float k7)
{
    float e = dtc*(E1c*k1 + E3c*k3 + E4c*k4 + E5c*k5 + E6c*k6 + E7c*k7);
    float tol = ATOL + RTOL*fmaxf(fabsf(yv), fabsf(y5v));
    float r = e / tol;
    return r*r;
}

__global__ __launch_bounds__(256)
void k_err(const float* __restrict__ sc, const float4* __restrict__ y,
           const float4* __restrict__ y5v, const float4* __restrict__ kb,
           float* __restrict__ part)
{
    if (sc[3] != 0.0f) return;
    float t = sc[0], dt = sc[1];
    float dtc = fminf(dt, 1.0f - t);
    const int n4 = NS/4;
    int tid = threadIdx.x;
    float lsum = 0.0f;
    for (int i = blockIdx.x*256 + tid; i < n4; i += 256*256) {
        float4 yv = y[i], y5 = y5v[i];
        float4 k1 = kb[i], k3 = kb[2*n4 + i], k4 = kb[3*n4 + i],
               k5 = kb[4*n4 + i], k6 = kb[5*n4 + i], k7 = kb[6*n4 + i];
        lsum += err_comp(dtc, yv.x, y5.x, k1.x, k3.x, k4.x, k5.x, k6.x, k7.x);
        lsum += err_comp(dtc, yv.y, y5.y, k1.y, k3.y, k4.y, k5.y, k6.y, k7.y);
        lsum += err_comp(dtc, yv.z, y5.z, k1.z, k3.z, k4.z, k5.z, k6.z, k7.z);
        lsum += err_comp(dtc, yv.w, y5.w, k1.w, k3.w, k4.w, k5.w, k6.w, k7.w);
    }
    __shared__ float red[256];
    red[tid] = lsum;
    __syncthreads();
    for (int s = 128; s > 0; s >>= 1) {
        if (tid < s) red[tid] += red[tid + s];
        __syncthreads();
    }
    if (tid == 0) part[blockIdx.x] = red[0];
}

// ---------------- control: scalar step update ----------------
__global__ void k_control(float* __restrict__ sc, const float* __restrict__ part)
{
    __shared__ float red[256];
    int tid = threadIdx.x;
    float done = sc[3];
    red[tid] = part[tid];
    __syncthreads();
    for (int s = 128; s > 0; s >>= 1) {
        if (tid < s) red[tid] += red[tid + s];
        __syncthreads();
    }
    if (tid == 0) {
        if (done != 0.0f) { sc[2] = 0.0f; return; }
        float t = sc[0], dt = sc[1];
        float dtc = fminf(dt, 1.0f - t);
        float err_norm = sqrtf(red[0] / (float)NS);
        bool adv = (err_norm <= 1.0f);
        float tn = adv ? (t + dtc) : t;
        float safe = fmaxf(err_norm, 1e-10f);
        float factor = 0.9f * powf(safe, -0.2f);
        factor = fminf(fmaxf(factor, 0.2f), 10.0f);
        float dtn = dtc * factor;
        sc[0] = tn;
        sc[1] = dtn;
        sc[2] = adv ? 1.0f : 0.0f;
        sc[3] = (tn >= 1.0f - 1e-7f) ? 1.0f : 0.0f;
    }
}

// ---------------- select: on accept, y<-y5 and k1<-k7 (FSAL) ----------------
__global__ __launch_bounds__(256)
void k_select(const float* __restrict__ sc, float4* __restrict__ y,
              const float4* __restrict__ y5, float4* __restrict__ k1,
              const float4* __restrict__ k7)
{
    if (sc[2] == 0.0f) return;
    int i = blockIdx.x*256 + threadIdx.x;
    y[i]  = y5[i];
    k1[i] = k7[i];
}

// ---------------- final linear head ----------------
__global__ __launch_bounds__(256)
void k_head(const float* __restrict__ y, const float* __restrict__ wl,
            const float* __restrict__ bl, float* __restrict__ out)
{
    int b = blockIdx.x;
    int tid = threadIdx.x;
    float acc[10];
    #pragma unroll
    for (int m = 0; m < 10; m++) acc[m] = 0.0f;
    for (int f = tid; f < 8192; f += 256) {
        float yv = y[(size_t)b*8192 + f];
        #pragma unroll
        for (int m = 0; m < 10; m++) acc[m] = fmaf(yv, wl[(size_t)m*8192 + f], acc[m]);
    }
    __shared__ float red[10][256];
    #pragma unroll
    for (int m = 0; m < 10; m++) red[m][tid] = acc[m];
    __syncthreads();
    for (int s = 128; s > 0; s >>= 1) {
        if (tid < s) {
            #pragma unroll
            for (int m = 0; m < 10; m++) red[m][tid] += red[m][tid + s];
        }
        __syncthreads();
    }
    if (tid < 10) out[b*10 + tid] = red[tid][0] + bl[tid];
}

// ---------------- host ----------------
extern "C" void kernel_launch(void* const* d_in, const int* in_sizes, int n_in,
                              void* d_out, int out_size, void* d_ws, size_t ws_size,
                              hipStream_t stream)
{
    const float* x  = (const float*)d_in[0];
    const float* w1 = (const float*)d_in[1];
    const float* b1 = (const float*)d_in[2];
    const float* w2 = (const float*)d_in[3];
    const float* b2 = (const float*)d_in[4];
    const float* w3 = (const float*)d_in[5];
    const float* b3 = (const float*)d_in[6];
    const float* wl = (const float*)d_in[7];
    const float* bl = (const float*)d_in[8];
    float* out = (float*)d_out;

    float* F    = (float*)d_ws;
    float* sc   = F + OFF_SC;
    float* part = F + OFF_PART;
    float* y    = F + OFF_Y;
    float* y5   = F + OFF_Y5;
    float* kb   = F + OFF_K;
    float* h1   = F + OFF_H1;
    float* h2   = F + OFF_H2;

    auto feval = [&](const float* src, int ncoef, Coefs cf, float ct, float* kout) {
        k_conv1<<<256, 256, 0, stream>>>(sc, src, kb, ncoef, cf, ct, w1, b1, h1);
        k_conv2<<<dim3(64, 2, 4), 256, 0, stream>>>(sc, h1, w2, b2, h2, ct);
        k_conv3<<<256, 256, 0, stream>>>(sc, h2, w3, b3, kout, ct);
    };

    k_init<<<NS/256, 256, 0, stream>>>(x, y, sc);
    feval(y, 0, Coefs{}, 0.0f, kb);                       // k1 = f(t0, y0)

    for (int s = 0; s < 24; s++) {
        feval(y, 1, Coefs{{A21}},                     C2f, kb + 1*(size_t)NS);
        feval(y, 2, Coefs{{A31, A32}},                C3f, kb + 2*(size_t)NS);
        feval(y, 3, Coefs{{A41, A42, A43}},           C4f, kb + 3*(size_t)NS);
        feval(y, 4, Coefs{{A51, A52, A53, A54}},      C5f, kb + 4*(size_t)NS);
        feval(y, 5, Coefs{{A61, A62, A63, A64, A65}}, 1.0f, kb + 5*(size_t)NS);
        k_y5<<<NS/4/256, 256, 0, stream>>>(sc, (const float4*)y, (const float4*)kb, (float4*)y5);
        feval(y5, 0, Coefs{}, 1.0f, kb + 6*(size_t)NS);   // k7 (FSAL)
        k_err<<<256, 256, 0, stream>>>(sc, (const float4*)y, (const float4*)y5,
                                       (const float4*)kb, part);
        k_control<<<1, 256, 0, stream>>>(sc, part);
        k_select<<<NS/4/256, 256, 0, stream>>>(sc, (float4*)y, (const float4*)y5,
                                               (float4*)kb, (const float4*)(kb + 6*(size_t)NS));
    }
    k_head<<<64, 256, 0, stream>>>(y, wl, bl, out);
}

// Round 2
// 1615.745 us; speedup vs baseline: 2.0391x; 2.0391x over previous
//
#include <hip/hip_runtime.h>
#include <math.h>

// ---------------- problem constants ----------------
namespace {
constexpr int BN = 64;        // batch
constexpr int HW = 1024;      // 32*32
constexpr int NS = BN*8*HW;   // 524288 state elems
constexpr int NH = BN*64*HW;  // 4194304 hidden elems

constexpr float C2f = 0.2f, C3f = 0.3f, C4f = 0.8f, C5f = (float)(8.0/9.0);
constexpr float A21 = 0.2f;
constexpr float A31 = (float)(3.0/40.0),  A32 = (float)(9.0/40.0);
constexpr float A41 = (float)(44.0/45.0), A42 = (float)(-56.0/15.0), A43 = (float)(32.0/9.0);
constexpr float A51 = (float)(19372.0/6561.0), A52 = (float)(-25360.0/2187.0),
                A53 = (float)(64448.0/6561.0), A54 = (float)(-212.0/729.0);
constexpr float A61 = (float)(9017.0/3168.0), A62 = (float)(-355.0/33.0),
                A63 = (float)(46732.0/5247.0), A64 = (float)(49.0/176.0),
                A65 = (float)(-5103.0/18656.0);
constexpr float B1c = (float)(35.0/384.0), B3c = (float)(500.0/1113.0),
                B4c = (float)(125.0/192.0), B5c = (float)(-2187.0/6784.0),
                B6c = (float)(11.0/84.0);
constexpr float E1c = (float)(71.0/57600.0), E3c = (float)(-71.0/16695.0),
                E4c = (float)(71.0/1920.0), E5c = (float)(-17253.0/339200.0),
                E6c = (float)(22.0/525.0),  E7c = (float)(-1.0/40.0);
constexpr float RTOL = 1e-3f, ATOL = 1e-3f;

// ws layout (floats). scalars: [0]=t [1]=dt [2]=adv [3]=done
constexpr size_t OFF_SC   = 0;
constexpr size_t OFF_PART = 16;                    // 256 partials
constexpr size_t OFF_TSUM = 512;                   // 9*64 floats
constexpr size_t OFF_W2P  = 1280;                  // 73728 ushorts = 36864 floats
constexpr size_t OFF_Y    = 38912;
constexpr size_t OFF_Y5   = OFF_Y    + (size_t)NS;
constexpr size_t OFF_K    = OFF_Y5   + (size_t)NS;     // 7*NS
constexpr size_t OFF_H1HI = OFF_K    + 7*(size_t)NS;   // NH/2 floats (NH ushorts)
constexpr size_t OFF_H1LO = OFF_H1HI + (size_t)NH/2;
constexpr size_t OFF_H2   = OFF_H1LO + (size_t)NH/2;   // NH floats
}

struct Coefs { float a[5]; };

typedef __bf16 bfrag8 __attribute__((ext_vector_type(8)));
typedef float f32x4 __attribute__((ext_vector_type(4)));

__device__ __forceinline__ unsigned short f2bf(float f) {
    unsigned u = __float_as_uint(f);
    unsigned r = u + 0x7fffu + ((u >> 16) & 1u);
    return (unsigned short)(r >> 16);
}
__device__ __forceinline__ float bf2f(unsigned short h) {
    return __uint_as_float(((unsigned)h) << 16);
}

// ---------------- init ----------------
__global__ __launch_bounds__(256)
void k_init(const float* __restrict__ x, float* __restrict__ y, float* __restrict__ sc)
{
    int idx = blockIdx.x*256 + threadIdx.x;
    int b = idx >> 13, c = (idx >> 10) & 7, p = idx & 1023;
    y[idx] = (c < 3) ? x[(size_t)(b*3 + c)*1024 + p] : 0.0f;
    if (idx == 0) { sc[0] = 0.0f; sc[1] = 0.1f; sc[2] = 0.0f; sc[3] = 0.0f; }
}

// ---------------- prepack w2 into MFMA B-frag order + t-channel mask table ----------------
__global__ __launch_bounds__(256)
void k_prepack(const float* __restrict__ w2, unsigned short* __restrict__ w2p,
               float* __restrict__ tsum)
{
    int gid = blockIdx.x*256 + threadIdx.x;
    if (gid < 73728) {
        int j    = gid & 7;
        int lane = (gid >> 3) & 63;
        int nt   = (gid >> 9) & 3;
        int r    = gid >> 11;            // (part*2+cc)*9 + tap
        int tap  = r % 9;
        int pc   = r / 9;
        int cc   = pc & 1, part = pc >> 1;
        int oc = nt*16 + (lane & 15);
        int ic = cc*32 + (lane >> 4)*8 + j;
        float wv = w2[oc*585 + (1 + ic)*9 + tap];
        unsigned short hi = f2bf(wv);
        w2p[gid] = (part == 0) ? hi : f2bf(wv - bf2f(hi));
    }
    if (gid < 576) {
        int oc = gid & 63, combo = gid >> 6;       // 0..8
        int rcase = combo / 3, ccase = combo % 3;
        float s = 0.0f;
        for (int kh = 0; kh < 3; kh++) {
            if ((rcase == 1 && kh == 0) || (rcase == 2 && kh == 2)) continue;
            for (int kw = 0; kw < 3; kw++) {
                if ((ccase == 1 && kw == 0) || (ccase == 2 && kw == 2)) continue;
                s += w2[oc*585 + kh*3 + kw];
            }
        }
        tsum[gid] = s;
    }
}

// ---------------- conv1: z-combine + 1x1 conv 9->64 + relu -> bf16 hi/lo px-major ----------------
__global__ __launch_bounds__(256)
void k_conv1(const float* __restrict__ sc, const float* __restrict__ src,
             const float* __restrict__ kb, int ncoef, Coefs cf, float ct,
             const float* __restrict__ w1, const float* __restrict__ b1,
             unsigned* __restrict__ h1hi, unsigned* __restrict__ h1lo)
{
    if (sc[3] != 0.0f) return;
    __shared__ __align__(16) float s_wt[8][64];
    __shared__ float s_w0[64];
    __shared__ float s_b[64];
    int tid = threadIdx.x;
    if (tid < 64) {
        s_b[tid]  = b1[tid];
        s_w0[tid] = w1[tid*9];
        #pragma unroll
        for (int c = 0; c < 8; c++) s_wt[c][tid] = w1[tid*9 + 1 + c];
    }
    __syncthreads();
    float t = sc[0], dt = sc[1];
    float dtc = fminf(dt, 1.0f - t);
    float ts  = t + ct*dtc;
    int gid = blockIdx.x*256 + tid;
    int b = gid >> 10, p = gid & 1023;

    float z[8];
    #pragma unroll
    for (int c = 0; c < 8; c++) {
        size_t idx = (size_t)(b*8 + c)*HW + p;
        float s = 0.0f;
        for (int j = 0; j < ncoef; j++) s += cf.a[j]*kb[(size_t)j*NS + idx];
        z[c] = src[idx] + dtc*s;
    }
    float acc[64];
    #pragma unroll
    for (int o = 0; o < 64; o++) acc[o] = fmaf(ts, s_w0[o], s_b[o]);
    #pragma unroll
    for (int c = 0; c < 8; c++) {
        float zc = z[c];
        const float4* w4 = reinterpret_cast<const float4*>(&s_wt[c][0]);
        #pragma unroll
        for (int q = 0; q < 16; q++) {
            float4 w = w4[q];
            acc[4*q+0] = fmaf(w.x, zc, acc[4*q+0]);
            acc[4*q+1] = fmaf(w.y, zc, acc[4*q+1]);
            acc[4*q+2] = fmaf(w.z, zc, acc[4*q+2]);
            acc[4*q+3] = fmaf(w.w, zc, acc[4*q+3]);
        }
    }
    unsigned hibuf[32], lobuf[32];
    #pragma unroll
    for (int i = 0; i < 32; i++) {
        float f0 = fmaxf(acc[2*i],   0.0f);
        float f1 = fmaxf(acc[2*i+1], 0.0f);
        unsigned short h0 = f2bf(f0), h1v = f2bf(f1);
        unsigned short l0 = f2bf(f0 - bf2f(h0)), l1 = f2bf(f1 - bf2f(h1v));
        hibuf[i] = (unsigned)h0 | ((unsigned)h1v << 16);
        lobuf[i] = (unsigned)l0 | ((unsigned)l1 << 16);
    }
    uint4* dh = (uint4*)(h1hi + (size_t)gid*32);
    uint4* dl = (uint4*)(h1lo + (size_t)gid*32);
    #pragma unroll
    for (int i = 0; i < 8; i++) {
        dh[i] = ((const uint4*)hibuf)[i];
        dl[i] = ((const uint4*)lobuf)[i];
    }
}

// ---------------- conv2: 3x3 65->64 via split-bf16 MFMA, h2 in [b][px][oc] ----------------
__global__ __launch_bounds__(256)
void k_conv2(const float* __restrict__ sc, const unsigned* __restrict__ h1hi,
             const unsigned* __restrict__ h1lo, const unsigned short* __restrict__ w2p,
             const float* __restrict__ tsum, const float* __restrict__ b2,
             float* __restrict__ h2, float ct)
{
    if (sc[3] != 0.0f) return;
    __shared__ __align__(16) unsigned short s_hi[6*34*32];
    __shared__ __align__(16) unsigned short s_lo[6*34*32];
    int tid = threadIdx.x;
    int b = blockIdx.x, rg = blockIdx.y;
    int w = tid >> 6, lane = tid & 63, l15 = lane & 15, q = lane >> 4;
    float t = sc[0], dt = sc[1];
    float dtc = fminf(dt, 1.0f - t);
    float ts  = t + ct*dtc;

    f32x4 acc[2][4];
    #pragma unroll
    for (int mt = 0; mt < 2; mt++)
        #pragma unroll
        for (int nt = 0; nt < 4; nt++) acc[mt][nt] = (f32x4){0.f,0.f,0.f,0.f};

    for (int cc = 0; cc < 2; cc++) {
        // stage activations (6 rows x 34 cols x 32 ic, hi+lo), zero-padded halo
        for (int i = tid; i < 1632; i += 256) {
            int part = i >= 816;
            int e = part ? i - 816 : i;
            int g  = e & 3;
            int t2 = e >> 2;                 // row*34 + col
            int row = t2 / 34;
            int col = t2 - row*34;
            int r = rg*4 - 1 + row;
            int c = col - 1;
            uint4 v = make_uint4(0u,0u,0u,0u);
            if ((unsigned)r < 32u && (unsigned)c < 32u) {
                const unsigned* srcp = (part ? h1lo : h1hi)
                    + ((size_t)((b << 10) + (r << 5) + c))*32 + cc*16 + g*4;
                v = *(const uint4*)srcp;
            }
            unsigned short* dst = (part ? s_lo : s_hi) + t2*32 + g*8;
            *(uint4*)dst = v;
        }
        __syncthreads();

        const unsigned short* wp_hi = w2p + (size_t)(cc*9)*2048;
        const unsigned short* wp_lo = w2p + (size_t)((2 + cc)*9)*2048;
        #pragma unroll 1
        for (int kh = 0; kh < 3; kh++) {
            #pragma unroll
            for (int kw = 0; kw < 3; kw++) {
                int tap = kh*3 + kw;
                bfrag8 bh[4], bl[4];
                #pragma unroll
                for (int nt = 0; nt < 4; nt++) {
                    bh[nt] = *(const bfrag8*)(wp_hi + (size_t)(tap*4 + nt)*512 + lane*8);
                    bl[nt] = *(const bfrag8*)(wp_lo + (size_t)(tap*4 + nt)*512 + lane*8);
                }
                int lr = w + kh;
                #pragma unroll
                for (int mt = 0; mt < 2; mt++) {
                    int lc = mt*16 + l15 + kw;
                    int off = (lr*34 + lc)*32 + q*8;
                    bfrag8 ah = *(const bfrag8*)(s_hi + off);
                    bfrag8 al = *(const bfrag8*)(s_lo + off);
                    #pragma unroll
                    for (int nt = 0; nt < 4; nt++) {
                        acc[mt][nt] = __builtin_amdgcn_mfma_f32_16x16x32_bf16(ah, bh[nt], acc[mt][nt], 0, 0, 0);
                        acc[mt][nt] = __builtin_amdgcn_mfma_f32_16x16x32_bf16(ah, bl[nt], acc[mt][nt], 0, 0, 0);
                        acc[mt][nt] = __builtin_amdgcn_mfma_f32_16x16x32_bf16(al, bh[nt], acc[mt][nt], 0, 0, 0);
                    }
                }
            }
        }
        __syncthreads();
    }

    // epilogue: + ts * t-channel mask sum + bias, relu, store
    int r_out = rg*4 + w;
    int rcase = (r_out == 0) ? 1 : ((r_out == 31) ? 2 : 0);
    #pragma unroll
    for (int mt = 0; mt < 2; mt++) {
        #pragma unroll
        for (int reg = 0; reg < 4; reg++) {
            int c = mt*16 + q*4 + reg;
            int ccase = (c == 0) ? 1 : ((c == 31) ? 2 : 0);
            const float* tsp = tsum + (rcase*3 + ccase)*64;
            float* outp = h2 + ((size_t)((b << 10) + (r_out << 5) + c))*64;
            #pragma unroll
            for (int nt = 0; nt < 4; nt++) {
                int oc = nt*16 + l15;
                float v = acc[mt][nt][reg] + ts*tsp[oc] + b2[oc];
                outp[oc] = fmaxf(v, 0.0f);
            }
        }
    }
}

// ---------------- conv3: 1x1 65->8; mode1 fuses y5, mode2 fuses err partial ----------------
__global__ __launch_bounds__(256)
void k_conv3(const float* __restrict__ sc, const float* __restrict__ h2,
             const float* __restrict__ w3, const float* __restrict__ b3,
             float* __restrict__ kout, float ct, int mode,
             const float* __restrict__ y, const float* __restrict__ y5,
             float* __restrict__ y5out, const float* __restrict__ kb,
             float* __restrict__ part)
{
    if (sc[3] != 0.0f) return;
    __shared__ __align__(16) float s_wt[64][8];
    __shared__ float s_w0[8], s_b[8];
    int tid = threadIdx.x;
    if (tid < 64) {
        #pragma unroll
        for (int o = 0; o < 8; o++) s_wt[tid][o] = w3[o*65 + 1 + tid];
        if (tid < 8) { s_w0[tid] = w3[tid*65]; s_b[tid] = b3[tid]; }
    }
    __syncthreads();
    float t = sc[0], dt = sc[1];
    float dtc = fminf(dt, 1.0f - t);
    float ts  = t + ct*dtc;
    int gid = blockIdx.x*256 + tid;
    int b = gid >> 10, p = gid & 1023;

    float acc[8];
    #pragma unroll
    for (int o = 0; o < 8; o++) acc[o] = fmaf(ts, s_w0[o], s_b[o]);
    const float4* hv4 = (const float4*)(h2 + (size_t)gid*64);
    #pragma unroll 4
    for (int i = 0; i < 16; i++) {
        float4 h = hv4[i];
        float hv[4] = {h.x, h.y, h.z, h.w};
        #pragma unroll
        for (int u = 0; u < 4; u++) {
            int c = i*4 + u;
            const float4* w4 = (const float4*)&s_wt[c][0];
            float4 wA = w4[0], wB = w4[1];
            float x = hv[u];
            acc[0] = fmaf(wA.x, x, acc[0]);
            acc[1] = fmaf(wA.y, x, acc[1]);
            acc[2] = fmaf(wA.z, x, acc[2]);
            acc[3] = fmaf(wA.w, x, acc[3]);
            acc[4] = fmaf(wB.x, x, acc[4]);
            acc[5] = fmaf(wB.y, x, acc[5]);
            acc[6] = fmaf(wB.z, x, acc[6]);
            acc[7] = fmaf(wB.w, x, acc[7]);
        }
    }

    size_t id0 = ((size_t)b*8)*1024 + p;
    if (mode == 0) {
        #pragma unroll
        for (int c = 0; c < 8; c++) kout[id0 + (size_t)c*1024] = acc[c];
    } else if (mode == 1) {
        #pragma unroll
        for (int c = 0; c < 8; c++) {
            size_t id = id0 + (size_t)c*1024;
            float k1v = kb[id];
            float k3v = kb[id + 2*(size_t)NS];
            float k4v = kb[id + 3*(size_t)NS];
            float k5v = kb[id + 4*(size_t)NS];
            kout[id] = acc[c];
            y5out[id] = y[id] + dtc*(B1c*k1v + B3c*k3v + B4c*k4v + B5c*k5v + B6c*acc[c]);
        }
    } else {
        float ls = 0.0f;
        #pragma unroll
        for (int c = 0; c < 8; c++) {
            size_t id = id0 + (size_t)c*1024;
            float k1v = kb[id];
            float k3v = kb[id + 2*(size_t)NS];
            float k4v = kb[id + 3*(size_t)NS];
            float k5v = kb[id + 4*(size_t)NS];
            float k6v = kb[id + 5*(size_t)NS];
            float e = dtc*(E1c*k1v + E3c*k3v + E4c*k4v + E5c*k5v + E6c*k6v + E7c*acc[c]);
            float tol = ATOL + RTOL*fmaxf(fabsf(y[id]), fabsf(y5[id]));
            float r = e / tol;
            ls += r*r;
            kout[id] = acc[c];
        }
        __shared__ float red[256];
        red[tid] = ls;
        __syncthreads();
        for (int s = 128; s > 0; s >>= 1) {
            if (tid < s) red[tid] += red[tid + s];
            __syncthreads();
        }
        if (tid == 0) part[blockIdx.x] = red[0];
    }
}

// ---------------- control ----------------
__global__ void k_control(float* __restrict__ sc, const float* __restrict__ part)
{
    __shared__ float red[256];
    int tid = threadIdx.x;
    float done = sc[3];
    red[tid] = part[tid];
    __syncthreads();
    for (int s = 128; s > 0; s >>= 1) {
        if (tid < s) red[tid] += red[tid + s];
        __syncthreads();
    }
    if (tid == 0) {
        if (done != 0.0f) { sc[2] = 0.0f; return; }
        float t = sc[0], dt = sc[1];
        float dtc = fminf(dt, 1.0f - t);
        float err_norm = sqrtf(red[0] / (float)NS);
        bool adv = (err_norm <= 1.0f);
        float tn = adv ? (t + dtc) : t;
        float safe = fmaxf(err_norm, 1e-10f);
        float factor = 0.9f * powf(safe, -0.2f);
        factor = fminf(fmaxf(factor, 0.2f), 10.0f);
        sc[0] = tn;
        sc[1] = dtc * factor;
        sc[2] = adv ? 1.0f : 0.0f;
        sc[3] = (tn >= 1.0f - 1e-7f) ? 1.0f : 0.0f;
    }
}

// ---------------- select (FSAL): on accept y<-y5, k1<-k7 ----------------
__global__ __launch_bounds__(256)
void k_select(const float* __restrict__ sc, float4* __restrict__ y,
              const float4* __restrict__ y5, float4* __restrict__ k1,
              const float4* __restrict__ k7)
{
    if (sc[2] == 0.0f) return;
    int i = blockIdx.x*256 + threadIdx.x;
    y[i]  = y5[i];
    k1[i] = k7[i];
}

// ---------------- final linear head ----------------
__global__ __launch_bounds__(256)
void k_head(const float* __restrict__ y, const float* __restrict__ wl,
            const float* __restrict__ bl, float* __restrict__ out)
{
    int b = blockIdx.x;
    int tid = threadIdx.x;
    float acc[10];
    #pragma unroll
    for (int m = 0; m < 10; m++) acc[m] = 0.0f;
    for (int f = tid; f < 8192; f += 256) {
        float yv = y[(size_t)b*8192 + f];
        #pragma unroll
        for (int m = 0; m < 10; m++) acc[m] = fmaf(yv, wl[(size_t)m*8192 + f], acc[m]);
    }
    __shared__ float red[10][256];
    #pragma unroll
    for (int m = 0; m < 10; m++) red[m][tid] = acc[m];
    __syncthreads();
    for (int s = 128; s > 0; s >>= 1) {
        if (tid < s) {
            #pragma unroll
            for (int m = 0; m < 10; m++) red[m][tid] += red[m][tid + s];
        }
        __syncthreads();
    }
    if (tid < 10) out[b*10 + tid] = red[tid][0] + bl[tid];
}

// ---------------- host ----------------
extern "C" void kernel_launch(void* const* d_in, const int* in_sizes, int n_in,
                              void* d_out, int out_size, void* d_ws, size_t ws_size,
                              hipStream_t stream)
{
    const float* x  = (const float*)d_in[0];
    const float* w1 = (const float*)d_in[1];
    const float* b1 = (const float*)d_in[2];
    const float* w2 = (const float*)d_in[3];
    const float* b2 = (const float*)d_in[4];
    const float* w3 = (const float*)d_in[5];
    const float* b3 = (const float*)d_in[6];
    const float* wl = (const float*)d_in[7];
    const float* bl = (const float*)d_in[8];
    float* out = (float*)d_out;

    float* F    = (float*)d_ws;
    float* sc   = F + OFF_SC;
    float* part = F + OFF_PART;
    float* tsum = F + OFF_TSUM;
    unsigned short* w2p = (unsigned short*)(F + OFF_W2P);
    float* y    = F + OFF_Y;
    float* y5   = F + OFF_Y5;
    float* kb   = F + OFF_K;
    unsigned* h1hi = (unsigned*)(F + OFF_H1HI);
    unsigned* h1lo = (unsigned*)(F + OFF_H1LO);
    float* h2   = F + OFF_H2;

    auto feval = [&](const float* src, int ncoef, Coefs cf, float ctv, int slot, int mode) {
        k_conv1<<<256, 256, 0, stream>>>(sc, src, kb, ncoef, cf, ctv, w1, b1, h1hi, h1lo);
        k_conv2<<<dim3(64, 8), 256, 0, stream>>>(sc, h1hi, h1lo, w2p, tsum, b2, h2, ctv);
        k_conv3<<<256, 256, 0, stream>>>(sc, h2, w3, b3, kb + (size_t)slot*NS, ctv, mode,
                                         y, y5, y5, kb, part);
    };

    k_init<<<NS/256, 256, 0, stream>>>(x, y, sc);
    k_prepack<<<288, 256, 0, stream>>>(w2, w2p, tsum);
    feval(y, 0, Coefs{}, 0.0f, 0, 0);                      // k1 = f(t0, y0)

    for (int s = 0; s < 24; s++) {
        feval(y, 1, Coefs{{A21}},                     C2f, 1, 0);
        feval(y, 2, Coefs{{A31, A32}},                C3f, 2, 0);
        feval(y, 3, Coefs{{A41, A42, A43}},           C4f, 3, 0);
        feval(y, 4, Coefs{{A51, A52, A53, A54}},      C5f, 4, 0);
        feval(y, 5, Coefs{{A61, A62, A63, A64, A65}}, 1.0f, 5, 1);  // k6 + y5
        feval(y5, 0, Coefs{},                         1.0f, 6, 2);  // k7 + err partials
        k_control<<<1, 256, 0, stream>>>(sc, part);
        k_select<<<NS/4/256, 256, 0, stream>>>(sc, (float4*)y, (const float4*)y5,
                                               (float4*)kb, (const float4*)(kb + 6*(size_t)NS));
    }
    k_head<<<64, 256, 0, stream>>>(y, wl, bl, out);
}

// Round 4
// 1216.391 us; speedup vs baseline: 2.7086x; 1.3283x over previous
//
#include <hip/hip_runtime.h>
#include <hip/hip_cooperative_groups.h>
#include <math.h>

namespace cg = cooperative_groups;

namespace {
constexpr int BN = 64;
constexpr int HW = 1024;
constexpr int NS = BN*8*HW;      // 524288

constexpr float C2f = 0.2f, C3f = 0.3f, C4f = 0.8f, C5f = (float)(8.0/9.0);
constexpr float A21 = 0.2f;
constexpr float A31 = (float)(3.0/40.0),  A32 = (float)(9.0/40.0);
constexpr float A41 = (float)(44.0/45.0), A42 = (float)(-56.0/15.0), A43 = (float)(32.0/9.0);
constexpr float A51 = (float)(19372.0/6561.0), A52 = (float)(-25360.0/2187.0),
                A53 = (float)(64448.0/6561.0), A54 = (float)(-212.0/729.0);
constexpr float A61 = (float)(9017.0/3168.0), A62 = (float)(-355.0/33.0),
                A63 = (float)(46732.0/5247.0), A64 = (float)(49.0/176.0),
                A65 = (float)(-5103.0/18656.0);
constexpr float B1c = (float)(35.0/384.0), B3c = (float)(500.0/1113.0),
                B4c = (float)(125.0/192.0), B5c = (float)(-2187.0/6784.0),
                B6c = (float)(11.0/84.0);
constexpr float E1c = (float)(71.0/57600.0), E3c = (float)(-71.0/16695.0),
                E4c = (float)(71.0/1920.0), E5c = (float)(-17253.0/339200.0),
                E6c = (float)(22.0/525.0),  E7c = (float)(-1.0/40.0);
constexpr float RTOL = 1e-3f, ATOL = 1e-3f;

// ws layout (floats)
constexpr size_t OFF_PART = 0;        // 512
constexpr size_t OFF_TSUM = 512;      // 576
constexpr size_t OFF_W2P  = 1088;     // 73728 ushorts = 36864 floats
constexpr size_t OFF_Y    = 37952;
constexpr size_t OFF_Y5   = OFF_Y  + (size_t)NS;
constexpr size_t OFF_K    = OFF_Y5 + (size_t)NS;   // 7*NS (k1..k7 slots)
}

__constant__ float g_cf[6][5] = {
    {A21, 0, 0, 0, 0},
    {A31, A32, 0, 0, 0},
    {A41, A42, A43, 0, 0},
    {A51, A52, A53, A54, 0},
    {A61, A62, A63, A64, A65},
    {0, 0, 0, 0, 0}};
__constant__ float g_ct[6] = {C2f, C3f, C4f, C5f, 1.0f, 1.0f};

typedef __bf16 bfrag8 __attribute__((ext_vector_type(8)));
typedef float f32x4 __attribute__((ext_vector_type(4)));

__device__ __forceinline__ unsigned short f2bf(float f) {
    unsigned u = __float_as_uint(f);
    unsigned r = u + 0x7fffu + ((u >> 16) & 1u);
    return (unsigned short)(r >> 16);
}
__device__ __forceinline__ float bf2f(unsigned short h) {
    return __uint_as_float(((unsigned)h) << 16);
}

// ---------------- init: y0 = concat(x, zeros) ----------------
__global__ __launch_bounds__(256)
void k_init(const float* __restrict__ x, float* __restrict__ y)
{
    int idx = blockIdx.x*256 + threadIdx.x;
    int b = idx >> 13, c = (idx >> 10) & 7, p = idx & 1023;
    y[idx] = (c < 3) ? x[(size_t)(b*3 + c)*1024 + p] : 0.0f;
}

// ---------------- prepack w2 into MFMA B-frag order + t-channel mask table ----------------
__global__ __launch_bounds__(256)
void k_prepack(const float* __restrict__ w2, unsigned short* __restrict__ w2p,
               float* __restrict__ tsum)
{
    int gid = blockIdx.x*256 + threadIdx.x;
    if (gid < 73728) {
        int j    = gid & 7;
        int lane = (gid >> 3) & 63;
        int nt   = (gid >> 9) & 3;
        int r    = gid >> 11;            // (part*2+cc)*9 + tap
        int tap  = r % 9;
        int pc   = r / 9;
        int cc   = pc & 1, part = pc >> 1;
        int oc = nt*16 + (lane & 15);
        int ic = cc*32 + (lane >> 4)*8 + j;
        float wv = w2[oc*585 + (1 + ic)*9 + tap];
        unsigned short hi = f2bf(wv);
        w2p[gid] = (part == 0) ? hi : f2bf(wv - bf2f(hi));
    }
    if (gid < 576) {
        int oc = gid & 63, combo = gid >> 6;       // 0..8
        int rcase = combo / 3, ccase = combo % 3;
        float s = 0.0f;
        for (int kh = 0; kh < 3; kh++) {
            if ((rcase == 1 && kh == 0) || (rcase == 2 && kh == 2)) continue;
            for (int kw = 0; kw < 3; kw++) {
                if ((ccase == 1 && kw == 0) || (ccase == 2 && kw == 2)) continue;
                s += w2[oc*585 + kh*3 + kw];
            }
        }
        tsum[gid] = s;
    }
}

// ---------------- the whole ODE solve: one cooperative kernel ----------------
// LDS budget: pool 55488 + persist 8256 = 63744 B  (< 64 KB workgroup limit)
__global__ void __launch_bounds__(256, 2)
k_ode(const float* __restrict__ w1, const float* __restrict__ b1,
      const float* __restrict__ b2, const float* __restrict__ w3,
      const float* __restrict__ b3, const unsigned short* __restrict__ w2p,
      const float* __restrict__ tsumg, const float* __restrict__ wl,
      const float* __restrict__ bl, float* __restrict__ ybuf,
      float* __restrict__ y5buf, float* __restrict__ kb,
      float* __restrict__ part, float* __restrict__ out)
{
    cg::grid_group grid = cg::this_grid();

    // activation pool: 6*34 px, 272 B/px = [hi ch0-31 | hi ch32-63 | lo ch0-31 | lo ch32-63 | 16B pad]
    __shared__ __align__(16) unsigned char s_pool[55488];
    __shared__ __align__(16) float s_w1t[8][64];
    __shared__ float s_w10[64], s_b1v[64];
    __shared__ __align__(16) float s_w3t[64][8];
    __shared__ float s_w30[8], s_b3v[8];
    __shared__ float s_tsum[576];
    __shared__ float s_b2v[64];
    __shared__ float s_red[256];

    const int tid = threadIdx.x;
    const int nblk = gridDim.x;
    const int wv  = tid >> 6, lane = tid & 63, l15 = lane & 15, q = lane >> 4;

    if (tid < 64) {
        s_b1v[tid] = b1[tid];
        s_w10[tid] = w1[tid*9];
        #pragma unroll
        for (int c = 0; c < 8; c++) s_w1t[c][tid] = w1[tid*9 + 1 + c];
        s_b2v[tid] = b2[tid];
        #pragma unroll
        for (int o = 0; o < 8; o++) s_w3t[tid][o] = w3[o*65 + 1 + tid];
        if (tid < 8) { s_w30[tid] = w3[tid*65]; s_b3v[tid] = b3[tid]; }
    }
    for (int i = tid; i < 576; i += 256) s_tsum[i] = tsumg[i];

    float t = 0.0f, dt = 0.1f;
    float* ya = ybuf; float* yb = y5buf;
    float* ka = kb;  float* kg = kb + 6*(size_t)NS;

    auto eval = [&](const float* src, int nc, const float* cf, float ctv,
                    float* kout, int mode) {
        float dtc = fminf(dt, 1.0f - t);
        float ts  = t + ctv*dtc;

        for (int tile = blockIdx.x; tile < 512; tile += nblk) {
            int b = tile >> 3, rg = tile & 7;

            // 1) zero activation pool (halo padding)
            {
                uint4 z4 = make_uint4(0u,0u,0u,0u);
                uint4* p4 = (uint4*)s_pool;
                for (int i = tid; i < 3468; i += 256) p4[i] = z4;
            }
            __syncthreads();

            // 2) conv1 (z-combine + 1x1 9->64 + relu) into LDS, 6 rows incl halo
            if (tid < 192) {
                int lr = tid >> 5, col = tid & 31;
                int r = rg*4 - 1 + lr;
                if ((unsigned)r < 32u) {
                    int px = (r << 5) + col;
                    float s[8] = {0,0,0,0,0,0,0,0};
                    for (int j = 0; j < nc; j++) {
                        const float* kp = (j == 0 ? ka : kb + (size_t)j*NS)
                                          + (((size_t)(b << 10) + px) << 3);
                        float4 kv0 = *(const float4*)kp;
                        float4 kv1 = *(const float4*)(kp + 4);
                        float a = cf[j];
                        s[0] += a*kv0.x; s[1] += a*kv0.y; s[2] += a*kv0.z; s[3] += a*kv0.w;
                        s[4] += a*kv1.x; s[5] += a*kv1.y; s[6] += a*kv1.z; s[7] += a*kv1.w;
                    }
                    float zz[8];
                    #pragma unroll
                    for (int c = 0; c < 8; c++)
                        zz[c] = src[((b*8 + c) << 10) + px] + dtc*s[c];
                    float acc[64];
                    #pragma unroll
                    for (int o = 0; o < 64; o++) acc[o] = fmaf(ts, s_w10[o], s_b1v[o]);
                    #pragma unroll
                    for (int c = 0; c < 8; c++) {
                        float zc = zz[c];
                        const float4* w4 = reinterpret_cast<const float4*>(&s_w1t[c][0]);
                        #pragma unroll
                        for (int qq = 0; qq < 16; qq++) {
                            float4 wq = w4[qq];
                            acc[4*qq+0] = fmaf(wq.x, zc, acc[4*qq+0]);
                            acc[4*qq+1] = fmaf(wq.y, zc, acc[4*qq+1]);
                            acc[4*qq+2] = fmaf(wq.z, zc, acc[4*qq+2]);
                            acc[4*qq+3] = fmaf(wq.w, zc, acc[4*qq+3]);
                        }
                    }
                    unsigned hibuf[32], lobuf[32];
                    #pragma unroll
                    for (int i = 0; i < 32; i++) {
                        float f0 = fmaxf(acc[2*i],   0.0f);
                        float f1 = fmaxf(acc[2*i+1], 0.0f);
                        unsigned short h0 = f2bf(f0), h1v = f2bf(f1);
                        unsigned short l0 = f2bf(f0 - bf2f(h0)), l1 = f2bf(f1 - bf2f(h1v));
                        hibuf[i] = (unsigned)h0 | ((unsigned)h1v << 16);
                        lobuf[i] = (unsigned)l0 | ((unsigned)l1 << 16);
                    }
                    int pxi = lr*34 + col + 1;
                    uint4* d = (uint4*)(s_pool + (size_t)pxi*272);
                    const uint4* hbv = (const uint4*)hibuf;
                    const uint4* lbv = (const uint4*)lobuf;
                    #pragma unroll
                    for (int i = 0; i < 8; i++) d[i] = hbv[i];        // hi: 128 B
                    #pragma unroll
                    for (int i = 0; i < 8; i++) d[8 + i] = lbv[i];    // lo: 128 B
                }
            }
            __syncthreads();

            // 3) conv2: 3x3 65->64 split-bf16 MFMA
            f32x4 acc2[2][4];
            #pragma unroll
            for (int mt = 0; mt < 2; mt++)
                #pragma unroll
                for (int nt = 0; nt < 4; nt++) acc2[mt][nt] = (f32x4){0.f,0.f,0.f,0.f};

            for (int cc = 0; cc < 2; cc++) {
                const unsigned short* wp_hi = w2p + (size_t)(cc*9)*2048;
                const unsigned short* wp_lo = w2p + (size_t)((2 + cc)*9)*2048;
                #pragma unroll 1
                for (int kh = 0; kh < 3; kh++) {
                    #pragma unroll
                    for (int kw = 0; kw < 3; kw++) {
                        int tap = kh*3 + kw;
                        bfrag8 bh[4], bl[4];
                        #pragma unroll
                        for (int nt = 0; nt < 4; nt++) {
                            bh[nt] = *(const bfrag8*)(wp_hi + (size_t)(tap*4 + nt)*512 + lane*8);
                            bl[nt] = *(const bfrag8*)(wp_lo + (size_t)(tap*4 + nt)*512 + lane*8);
                        }
                        int lr = wv + kh;
                        #pragma unroll
                        for (int mt = 0; mt < 2; mt++) {
                            int lc = mt*16 + l15 + kw;
                            const unsigned char* pxp = s_pool
                                + (size_t)(lr*34 + lc)*272 + cc*64 + q*16;
                            bfrag8 ah = *(const bfrag8*)pxp;
                            bfrag8 al = *(const bfrag8*)(pxp + 128);
                            #pragma unroll
                            for (int nt = 0; nt < 4; nt++) {
                                acc2[mt][nt] = __builtin_amdgcn_mfma_f32_16x16x32_bf16(ah, bh[nt], acc2[mt][nt], 0, 0, 0);
                                acc2[mt][nt] = __builtin_amdgcn_mfma_f32_16x16x32_bf16(ah, bl[nt], acc2[mt][nt], 0, 0, 0);
                                acc2[mt][nt] = __builtin_amdgcn_mfma_f32_16x16x32_bf16(al, bh[nt], acc2[mt][nt], 0, 0, 0);
                            }
                        }
                    }
                }
            }
            __syncthreads();   // before h2 overlay on pool

            // 4) epilogue: t-channel + bias + relu -> LDS h2, oc-major stride 129
            {
                float* s_h2 = (float*)s_pool;
                int r_out = rg*4 + wv;
                int rcase = (r_out == 0) ? 1 : ((r_out == 31) ? 2 : 0);
                #pragma unroll
                for (int mt = 0; mt < 2; mt++) {
                    #pragma unroll
                    for (int reg = 0; reg < 4; reg++) {
                        int c = mt*16 + q*4 + reg;
                        int ccase = (c == 0) ? 1 : ((c == 31) ? 2 : 0);
                        const float* tsp = s_tsum + (rcase*3 + ccase)*64;
                        int pxl = wv*32 + c;
                        #pragma unroll
                        for (int nt = 0; nt < 4; nt++) {
                            int oc = nt*16 + l15;
                            s_h2[oc*129 + pxl] =
                                fmaxf(acc2[mt][nt][reg] + ts*tsp[oc] + s_b2v[oc], 0.0f);
                        }
                    }
                }
            }
            __syncthreads();

            // 5) conv3 (1x1 65->8) + mode epilogues
            if (tid < 128) {
                const float* s_h2 = (const float*)s_pool;
                float a3[8];
                #pragma unroll
                for (int o = 0; o < 8; o++) a3[o] = fmaf(ts, s_w30[o], s_b3v[o]);
                #pragma unroll 8
                for (int c = 0; c < 64; c++) {
                    float xv = s_h2[c*129 + tid];
                    const float4* w4 = (const float4*)&s_w3t[c][0];
                    float4 wA = w4[0], wB = w4[1];
                    a3[0] = fmaf(wA.x, xv, a3[0]);
                    a3[1] = fmaf(wA.y, xv, a3[1]);
                    a3[2] = fmaf(wA.z, xv, a3[2]);
                    a3[3] = fmaf(wA.w, xv, a3[3]);
                    a3[4] = fmaf(wB.x, xv, a3[4]);
                    a3[5] = fmaf(wB.y, xv, a3[5]);
                    a3[6] = fmaf(wB.z, xv, a3[6]);
                    a3[7] = fmaf(wB.w, xv, a3[7]);
                }
                int px = rg*128 + tid;
                size_t pb8 = ((size_t)(b << 10) + px) << 3;
                *(float4*)(kout + pb8)     = make_float4(a3[0], a3[1], a3[2], a3[3]);
                *(float4*)(kout + pb8 + 4) = make_float4(a3[4], a3[5], a3[6], a3[7]);
                if (mode == 1) {
                    const float* k1p = ka + pb8;
                    const float* k3p = kb + 2*(size_t)NS + pb8;
                    const float* k4p = kb + 3*(size_t)NS + pb8;
                    const float* k5p = kb + 4*(size_t)NS + pb8;
                    #pragma unroll
                    for (int c = 0; c < 8; c++) {
                        size_t id = ((size_t)(b*8 + c) << 10) + px;
                        yb[id] = ya[id] + dtc*(B1c*k1p[c] + B3c*k3p[c] + B4c*k4p[c]
                                               + B5c*k5p[c] + B6c*a3[c]);
                    }
                } else if (mode == 2) {
                    const float* k1p = ka + pb8;
                    const float* k3p = kb + 2*(size_t)NS + pb8;
                    const float* k4p = kb + 3*(size_t)NS + pb8;
                    const float* k5p = kb + 4*(size_t)NS + pb8;
                    const float* k6p = kb + 5*(size_t)NS + pb8;
                    float ls = 0.0f;
                    #pragma unroll
                    for (int c = 0; c < 8; c++) {
                        size_t id = ((size_t)(b*8 + c) << 10) + px;
                        float e = dtc*(E1c*k1p[c] + E3c*k3p[c] + E4c*k4p[c]
                                       + E5c*k5p[c] + E6c*k6p[c] + E7c*a3[c]);
                        float tol = ATOL + RTOL*fmaxf(fabsf(ya[id]), fabsf(yb[id]));
                        float rr = e / tol;
                        ls += rr*rr;
                    }
                    s_red[tid] = ls;
                }
            }
            if (mode == 2) {
                if (tid >= 128) s_red[tid] = 0.0f;
                __syncthreads();
                for (int sft = 128; sft > 0; sft >>= 1) {
                    if (tid < sft) s_red[tid] += s_red[tid + sft];
                    __syncthreads();
                }
                if (tid == 0) part[tile] = s_red[0];
            }
            __syncthreads();   // protect pool before next tile
        }
        grid.sync();
    };

    // k1 = f(t0, y0)
    eval(ya, 0, g_cf[5], 0.0f, ka, 0);

    for (int st = 0; st < 24; st++) {
        if (t >= 1.0f - 1e-7f) break;
        for (int e = 0; e < 6; e++) {
            int nc = (e < 5) ? e + 1 : 0;
            const float* src = (e == 5) ? yb : ya;
            float* kout = (e < 5) ? kb + (size_t)(e + 1)*NS : kg;
            int mode = (e == 4) ? 1 : ((e == 5) ? 2 : 0);
            eval(src, nc, g_cf[e], g_ct[e], kout, mode);
        }
        // control: every block reduces the same 512 partials identically
        float v = part[tid] + part[tid + 256];
        s_red[tid] = v;
        __syncthreads();
        for (int sft = 128; sft > 0; sft >>= 1) {
            if (tid < sft) s_red[tid] += s_red[tid + sft];
            __syncthreads();
        }
        float red0 = s_red[0];
        __syncthreads();
        float err_norm = sqrtf(red0 / (float)NS);
        float dtc = fminf(dt, 1.0f - t);
        bool adv = (err_norm <= 1.0f);
        if (adv) {
            t = t + dtc;
            float* tmp = ya; ya = yb; yb = tmp;   // y <- y5
            tmp = ka; ka = kg; kg = tmp;          // k1 <- k7 (FSAL)
        }
        float safe = fmaxf(err_norm, 1e-10f);
        float factor = fminf(fmaxf(0.9f*powf(safe, -0.2f), 0.2f), 10.0f);
        dt = dtc*factor;
    }

    // final linear head
    __syncthreads();
    for (int bh = blockIdx.x; bh < 64; bh += nblk) {
        float* s_hred = (float*)s_pool;   // 10*256 floats overlay
        float acc[10];
        #pragma unroll
        for (int m = 0; m < 10; m++) acc[m] = 0.0f;
        for (int f = tid; f < 8192; f += 256) {
            float yv = ya[(size_t)bh*8192 + f];
            #pragma unroll
            for (int m = 0; m < 10; m++) acc[m] = fmaf(yv, wl[(size_t)m*8192 + f], acc[m]);
        }
        #pragma unroll
        for (int m = 0; m < 10; m++) s_hred[m*256 + tid] = acc[m];
        __syncthreads();
        for (int sft = 128; sft > 0; sft >>= 1) {
            if (tid < sft) {
                #pragma unroll
                for (int m = 0; m < 10; m++)
                    s_hred[m*256 + tid] += s_hred[m*256 + tid + sft];
            }
            __syncthreads();
        }
        if (tid < 10) out[bh*10 + tid] = s_hred[tid*256] + bl[tid];
        __syncthreads();
    }
}

// ---------------- host ----------------
extern "C" void kernel_launch(void* const* d_in, const int* in_sizes, int n_in,
                              void* d_out, int out_size, void* d_ws, size_t ws_size,
                              hipStream_t stream)
{
    const float* x  = (const float*)d_in[0];
    const float* w1 = (const float*)d_in[1];
    const float* b1 = (const float*)d_in[2];
    const float* w2 = (const float*)d_in[3];
    const float* b2 = (const float*)d_in[4];
    const float* w3 = (const float*)d_in[5];
    const float* b3 = (const float*)d_in[6];
    const float* wl = (const float*)d_in[7];
    const float* bl = (const float*)d_in[8];
    float* out = (float*)d_out;

    float* F = (float*)d_ws;
    float* part = F + OFF_PART;
    float* tsum = F + OFF_TSUM;
    unsigned short* w2p = (unsigned short*)(F + OFF_W2P);
    float* y    = F + OFF_Y;
    float* y5   = F + OFF_Y5;
    float* kbp  = F + OFF_K;

    k_init<<<NS/256, 256, 0, stream>>>(x, y);
    k_prepack<<<288, 256, 0, stream>>>(w2, w2p, tsum);

    // size the cooperative grid to guaranteed co-residency
    int maxb = 0;
    if (hipOccupancyMaxActiveBlocksPerMultiprocessor(&maxb,
            reinterpret_cast<const void*>(k_ode), 256, 0) != hipSuccess || maxb < 1)
        maxb = 1;
    int cus = 256;
    {
        int dev = 0;
        hipGetDevice(&dev);
        hipDeviceProp_t prop;
        if (hipGetDeviceProperties(&prop, dev) == hipSuccess && prop.multiProcessorCount > 0)
            cus = prop.multiProcessorCount;
    }
    long cap = (long)maxb * (long)cus;
    int gridn = (int)((cap < 512) ? cap : 512);
    if (gridn < 1) gridn = 1;

    void* args[] = {
        (void*)&w1, (void*)&b1, (void*)&b2, (void*)&w3, (void*)&b3,
        (void*)&w2p, (void*)&tsum, (void*)&wl, (void*)&bl,
        (void*)&y, (void*)&y5, (void*)&kbp, (void*)&part, (void*)&out
    };
    hipLaunchCooperativeKernel((void*)k_ode, dim3(gridn), dim3(256), args, 0, stream);
}